// Round 21
// baseline (109.774 us; speedup 1.0000x reference)
//
#include <hip/hip_runtime.h>

typedef _Float16 f16;
typedef __attribute__((ext_vector_type(8))) _Float16 f16x8;
typedef __attribute__((ext_vector_type(4))) _Float16 f16x4;
typedef __attribute__((ext_vector_type(4))) float f32x4;

#define B_ 4
#define N_ 2048
#define DIM_ 512
#define H_ 8
#define DH_ 64

// global -> LDS direct (16B per lane). LDS dest must be wave-uniform;
// global src is per-lane (pre-swizzled). Size must be literal 16.
__device__ __forceinline__ void gload16(const void* g, void* l) {
    __builtin_amdgcn_global_load_lds((const __attribute__((address_space(1))) void*)g,
                                     (__attribute__((address_space(3))) void*)l, 16, 0, 0);
}

// ---------------- fused prep: x cvt + both weight transposes (one launch) ----------------
__global__ __launch_bounds__(256) void prep_k(
    const float* __restrict__ x, f16* __restrict__ x16,
    const float* __restrict__ w_qkvg, f16* __restrict__ wqT,
    const float* __restrict__ w_out, f16* __restrict__ woT)
{
    __shared__ f16 tile[64][72];
    const int bid = blockIdx.x;
    const int t = threadIdx.x;
    if (bid < 2048) {
        int i = bid * 256 + t;                 // n8 = 524288
        const float4 a = ((const float4*)x)[i * 2];
        const float4 b = ((const float4*)x)[i * 2 + 1];
        f16x8 o = {(f16)a.x, (f16)a.y, (f16)a.z, (f16)a.w,
                   (f16)b.x, (f16)b.y, (f16)b.z, (f16)b.w};
        ((f16x8*)x16)[i] = o;
        return;
    }
    const float* in; f16* out; int K, N, lb;
    if (bid < 2304) { in = w_qkvg; out = wqT; K = 512; N = 2048; lb = bid - 2048; }
    else            { in = w_out;  out = woT; K = 1024; N = 512;  lb = bid - 2304; }
    const int nbk = K >> 6;
    const int bk = lb % nbk, bn = lb / nbk;
    const int k0 = bk << 6, n0 = bn << 6;
    const int r = t >> 2, q = (t & 3) << 4;
#pragma unroll
    for (int u = 0; u < 4; u++) {
        const float4 v = *(const float4*)&in[(size_t)(k0 + r) * N + n0 + q + u * 4];
        tile[q + u * 4 + 0][r] = (f16)v.x;
        tile[q + u * 4 + 1][r] = (f16)v.y;
        tile[q + u * 4 + 2][r] = (f16)v.z;
        tile[q + u * 4 + 3][r] = (f16)v.w;
    }
    __syncthreads();
#pragma unroll
    for (int u = 0; u < 2; u++) {
        f16x8 o = *(const f16x8*)&tile[r][q + u * 8];
        *(f16x8*)&out[(size_t)(n0 + r) * K + k0 + q + u * 8] = o;
    }
}

// ---------------- qkvg GEMM: 8-phase 256x256 template + LDS-transposed epilogue ----------------
__global__ __launch_bounds__(512, 2) void gemm0_8ph(
    const f16* __restrict__ A, const f16* __restrict__ BT,
    f16* __restrict__ qb, f16* __restrict__ kb, f16* __restrict__ vbT,
    f16* __restrict__ vs16)
{
    __shared__ char lds[131072];
    const int tid = threadIdx.x;
    const int bid = blockIdx.x;                 // 256 blocks = 1/CU
    const int xcd = bid & 7, w = bid >> 3;      // w in [0,32)
    const int m0 = ((xcd << 2) + (w >> 3)) << 8;   // 32 m-blocks of 256
    const int n0 = (w & 7) << 8;                   // 8 n-blocks of 256
    const int sec = (w & 7) >> 1, secHalf = w & 1; // section + head-half of this block
    const int wave = tid >> 6, lane = tid & 63;
    const int wr = wave >> 2, wc = wave & 3;       // 2M x 4N wave grid
    const int lr = lane & 15, lg = lane >> 4;

    f32x4 acc[8][4];
    const f32x4 zero = {0.f, 0.f, 0.f, 0.f};
#pragma unroll
    for (int i = 0; i < 8; i++)
#pragma unroll
        for (int j = 0; j < 4; j++) acc[i][j] = zero;

    const f16* gA[2][2]; const f16* gB[2][2];   // [half][u]
#pragma unroll
    for (int u = 0; u < 2; u++) {
        int c = tid + u * 512;
        int row = c >> 3;
        int e0 = (((c & 7) ^ (row & 7)) << 3);
#pragma unroll
        for (int h = 0; h < 2; h++) {
            gA[h][u] = A + (size_t)(m0 + h * 128 + row) * 512 + e0;
            gB[h][u] = BT + (size_t)(n0 + h * 128 + row) * 512 + e0;
        }
    }
    const int ldst = wave * 1024;

    // prologue: stage K-tile 0 into dbuf 0
#pragma unroll
    for (int h = 0; h < 2; h++)
#pragma unroll
        for (int u = 0; u < 2; u++)
            gload16(gA[h][u], lds + h * 16384 + ldst + u * 8192);
#pragma unroll
    for (int h = 0; h < 2; h++)
#pragma unroll
        for (int u = 0; u < 2; u++)
            gload16(gB[h][u], lds + 65536 + h * 16384 + ldst + u * 8192);

    const int swz = (lr & 7) << 4;
    for (int T = 0; T < 8; T++) {
        const int d = T & 1, d2 = (T + 1) & 1;
        const size_t Tn64 = (size_t)(T + 1) * 64;
        const char* Ab = lds + (d * 2 + wr) * 16384;
        const char* Bb = lds + 65536 + (d * 2 + (wc >> 1)) * 16384;
#pragma unroll
        for (int p = 0; p < 4; p++) {
            const int kh = p >> 1, qr = p & 1;
            if (T < 7) {                        // last tile: nothing left to stage
                if (p < 2) {
#pragma unroll
                    for (int u = 0; u < 2; u++)
                        gload16(gA[p][u] + Tn64, lds + (d2 * 2 + p) * 16384 + ldst + u * 8192);
                } else {
#pragma unroll
                    for (int u = 0; u < 2; u++)
                        gload16(gB[p - 2][u] + Tn64, lds + 65536 + (d2 * 2 + (p - 2)) * 16384 + ldst + u * 8192);
                }
            }
            if (p == 0) {
                if (T < 7) {
                    asm volatile("s_waitcnt vmcnt(2)" ::: "memory");
                } else {
                    asm volatile("s_waitcnt vmcnt(0)" ::: "memory");   // drain: T7 staged nothing
                }
            }
            __builtin_amdgcn_s_barrier();

            f16x8 af[4], bf[4];
            const int ko = (kh * 64 + lg * 16) ^ swz;
#pragma unroll
            for (int i = 0; i < 4; i++)
                af[i] = *(const f16x8*)(Ab + (qr * 64 + i * 16 + lr) * 128 + ko);
#pragma unroll
            for (int j = 0; j < 4; j++)
                bf[j] = *(const f16x8*)(Bb + ((wc & 1) * 64 + j * 16 + lr) * 128 + ko);
            asm volatile("s_waitcnt lgkmcnt(0)" ::: "memory");
            __builtin_amdgcn_sched_barrier(0);
            __builtin_amdgcn_s_setprio(1);
#pragma unroll
            for (int i = 0; i < 4; i++)
#pragma unroll
                for (int j = 0; j < 4; j++)
                    acc[qr * 4 + i][j] = __builtin_amdgcn_mfma_f32_16x16x32_f16(af[i], bf[j], acc[qr * 4 + i][j], 0, 0, 0);
            __builtin_amdgcn_s_setprio(0);
            __builtin_amdgcn_s_barrier();       // also gates epilogue LDS reuse (vmcnt==0 here)
        }
    }

    // ---- epilogue via LDS transpose (128KB = one 256x256 f16 tile) ----
    if (sec != 2) {
        const float scale = (sec == 0) ? 0.1803368801f : 1.0f;
#pragma unroll
        for (int fr = 0; fr < 8; fr++)
#pragma unroll
            for (int j = 0; j < 4; j++) {
                int nl = wc * 64 + j * 16 + lr;
                int mb = wr * 128 + fr * 16 + lg * 4;
#pragma unroll
                for (int r = 0; r < 4; r++) {
                    int m = mb + r;
                    *(f16*)(lds + m * 512 + ((nl * 2) ^ ((m & 7) << 4))) = (f16)(acc[fr][j][r] * scale);
                }
            }
        __syncthreads();
        f16* dst = (sec == 0) ? qb : (sec == 1 ? kb : vs16);
#pragma unroll
        for (int it = 0; it < 16; it++) {
            int ci = it * 512 + tid;
            int m = ci >> 5, nc = ci & 31;
            f16x8 vv = *(const f16x8*)(lds + m * 512 + ((nc * 16) ^ ((m & 7) << 4)));
            int n = nc * 8;
            int h = secHalf * 4 + (n >> 6), dd = n & 63;
            int gm = m0 + m, b = gm >> 11, ns = gm & 2047;
            *(f16x8*)&dst[((size_t)(b * H_ + h) * N_ + ns) * DH_ + dd] = vv;
        }
    } else {
#pragma unroll
        for (int fr = 0; fr < 8; fr++)
#pragma unroll
            for (int j = 0; j < 4; j++) {
                int n = wc * 64 + j * 16 + lr;
                int mb = wr * 128 + fr * 16 + lg * 4;
                f16x4 o;
#pragma unroll
                for (int r = 0; r < 4; r++) o[r] = (f16)acc[fr][j][r];
                *(f16x4*)(lds + n * 512 + ((mb * 2) ^ ((n & 7) << 4))) = o;
            }
        __syncthreads();
#pragma unroll
        for (int it = 0; it < 16; it++) {
            int ci = it * 512 + tid;
            int n = ci >> 5, mc = ci & 31;
            f16x8 vv = *(const f16x8*)(lds + n * 512 + ((mc * 16) ^ ((n & 7) << 4)));
            int h = secHalf * 4 + (n >> 6), dd = n & 63;
            int gm = m0 + mc * 8, b = gm >> 11, ns = gm & 2047;
            *(f16x8*)&vbT[((size_t)(b * H_ + h) * DH_ + dd) * N_ + ns] = vv;
        }
    }
}

// ---------------- small-N GEMM (final projection): 64x64 tile, BK=128 ----------------
__global__ __launch_bounds__(256) void gemm_small(
    const f16* __restrict__ A, const f16* __restrict__ BT, int K, int N,
    const float* __restrict__ bias, float* __restrict__ outp)
{
    __shared__ char sAb[16384];   // [64 m][128 k] f16
    __shared__ char sBb[16384];   // [64 n][128 k] f16
    const int tid = threadIdx.x;
    const int bid = blockIdx.x;                 // 1024
    const int xcd = bid & 7, w = bid >> 3;
    const int m0 = ((xcd << 4) + (w >> 3)) << 6;
    const int n0 = (w & 7) << 6;
    const int wave = tid >> 6, lane = tid & 63;
    const int wr = wave >> 1, wc = wave & 1;
    const int lr = lane & 15, lg = lane >> 4;

    f32x4 acc[2][2];
    const f32x4 zero = {0.f, 0.f, 0.f, 0.f};
#pragma unroll
    for (int i = 0; i < 2; i++)
#pragma unroll
        for (int j = 0; j < 2; j++) acc[i][j] = zero;

    const f16* srcA[4]; const f16* srcB[4];
    char* ldsA[4]; char* ldsB[4];
#pragma unroll
    for (int u = 0; u < 4; u++) {
        int c = tid + u * 256;
        int row = c >> 4;
        int e0 = (((c & 15) ^ (row & 7)) << 3);
        srcA[u] = A + (size_t)(m0 + row) * K + e0;
        srcB[u] = BT + (size_t)(n0 + row) * K + e0;
        ldsA[u] = sAb + wave * 1024 + u * 4096;
        ldsB[u] = sBb + wave * 1024 + u * 4096;
    }

    const int swz = (lr & 7) << 4;
    for (int kt = 0; kt < K; kt += 128) {
#pragma unroll
        for (int u = 0; u < 4; u++) {
            gload16(srcA[u], ldsA[u]);
            gload16(srcB[u], ldsB[u]);
            srcA[u] += 128; srcB[u] += 128;
        }
        __syncthreads();
#pragma unroll
        for (int khalf = 0; khalf < 4; khalf++) {
            const int ko = (khalf * 64 + lg * 16) ^ swz;
            f16x8 af[2], bf[2];
#pragma unroll
            for (int i = 0; i < 2; i++)
                af[i] = *(const f16x8*)(sAb + (wr * 32 + i * 16 + lr) * 256 + ko);
#pragma unroll
            for (int j = 0; j < 2; j++)
                bf[j] = *(const f16x8*)(sBb + (wc * 32 + j * 16 + lr) * 256 + ko);
#pragma unroll
            for (int i = 0; i < 2; i++)
#pragma unroll
                for (int j = 0; j < 2; j++)
                    acc[i][j] = __builtin_amdgcn_mfma_f32_16x16x32_f16(af[i], bf[j], acc[i][j], 0, 0, 0);
        }
        __syncthreads();
    }

#pragma unroll
    for (int i = 0; i < 2; i++)
#pragma unroll
        for (int j = 0; j < 2; j++) {
            int col = n0 + wc * 32 + j * 16 + lr;
            int row0 = m0 + wr * 32 + i * 16 + lg * 4;
#pragma unroll
            for (int r = 0; r < 4; r++)
                outp[(size_t)(row0 + r) * N + col] = acc[i][j][r] + bias[col];
        }
}

// ---------------- FUSED attention + gauss (one launch, independent work) ----------------
// Blocks 0..1023: gauss band conv (barrier-free, VALU/L2-bound) — dispatched
// FIRST so they backfill wave-slots that attn's barrier convoy leaves idle.
// Blocks 1024..2047: attn (R19 body: KV-split, K=32 PV, coalesced epilogue).
// combine runs as a separate kernel afterwards (reads attn outputs).
__global__ __launch_bounds__(256) void attn_gauss_k(
    const f16* __restrict__ qb, const f16* __restrict__ kb, const f16* __restrict__ vbT,
    const f16* __restrict__ vs16, const float* __restrict__ sigma,
    f16* __restrict__ cat, f16* __restrict__ oaccB, float* __restrict__ lacc)
{
    __shared__ char sKbf[2 * 8192];   // K bufs (attn), [64 kv][64 dh] f16, swizzled
    __shared__ char sVbf[2 * 8192];   // V bufs (attn)
    const int tid = threadIdx.x;

    if (blockIdx.x < 1024) {
        // ================= gauss branch (independent of attn) =================
        const int gbid = blockIdx.x;
        const int bh = gbid & 31, b = bh >> 3, h = bh & 7;
        const int i0 = (gbid >> 5) * 64;
        const int wv = tid >> 6, d = tid & 63;
        const float sig = sigma[h];
        const float c = 0.72134752f / (sig * sig);   // log2(e)/(2 sig^2)

        float wt[17];
#pragma unroll
        for (int o = 0; o <= 16; o++) wt[o] = __builtin_amdgcn_exp2f(-(float)(o * o) * c);
        float wfull = wt[0];
#pragma unroll
        for (int o = 1; o <= 16; o++) wfull += 2.f * wt[o];
        const float inv_wfull = 1.0f / wfull;

        const size_t base = (size_t)bh * N_ * DH_;
        const int r0 = i0 + wv * 16 - 16;
        float v[48];
#pragma unroll
        for (int k = 0; k < 48; k++) {
            int r = r0 + k; r = r < 0 ? 0 : (r > N_ - 1 ? N_ - 1 : r);
            v[k] = (float)vs16[base + (size_t)r * DH_ + d];
        }

#pragma unroll
        for (int it = 0; it < 16; it++) {
            int i = i0 + wv * 16 + it;
            float acc = 0.f;
            if (i >= 16 && i <= N_ - 17) {
#pragma unroll
                for (int o = -16; o <= 16; o++)
                    acc += wt[o < 0 ? -o : o] * v[16 + it + o];
                acc *= inv_wfull;
            } else {
                float ws = 0.f;
#pragma unroll
                for (int o = -16; o <= 16; o++) {
                    int j = i + o;
                    if (j >= 0 && j <= N_ - 1) {
                        float w = wt[o < 0 ? -o : o];
                        ws += w;
                        acc += w * v[16 + it + o];
                    }
                }
                acc /= ws;
            }
            cat[((size_t)(b * N_ + i)) * 1024 + h * 128 + 64 + d] = (f16)acc;
        }
        return;
    }

    // ================= attn branch (R19 body) =================
    const int bid0 = blockIdx.x - 1024;
    const int obid = (bid0 & 7) * 128 + (bid0 >> 3);   // bijective XCD swizzle (1024 = 8*128)
    const int bh = obid >> 5, qblk = (obid >> 1) & 15, half = obid & 1;
    const int b = bh >> 3, h = bh & 7;
    const int hn = half << 4;                          // base kv tile of this half
    const int wave = tid >> 6, lane = tid & 63;
    const int lr = lane & 15, lg = lane >> 4;

    const size_t base = (size_t)bh * N_ * DH_;
    const int qrow_a = qblk * 128 + wave * 32 + lr;
    const int qrow_b = qrow_a + 16;
    const f16x8 qfa0 = *(const f16x8*)&qb[base + (size_t)qrow_a * DH_ + lg * 8];
    const f16x8 qfa1 = *(const f16x8*)&qb[base + (size_t)qrow_a * DH_ + 32 + lg * 8];
    const f16x8 qfb0 = *(const f16x8*)&qb[base + (size_t)qrow_b * DH_ + lg * 8];
    const f16x8 qfb1 = *(const f16x8*)&qb[base + (size_t)qrow_b * DH_ + 32 + lg * 8];

    const f16* kq[2]; const f16* vq[2];
#pragma unroll
    for (int u = 0; u < 2; u++) {
        int row = wave * 8 + u * 32 + (lane >> 3);
        int e0 = ((lane & 7) ^ (row & 7)) << 3;
        kq[u] = kb + base + (size_t)row * 64 + e0;
        vq[u] = vbT + base + (size_t)row * 2048 + e0;
    }
    char* const ldsKw = sKbf + wave * 1024;
    char* const ldsVw = sVbf + wave * 1024;

    f32x4 Ota[4], Otb[4], lacc_a, lacc_b;
    const f32x4 zero = {0.f, 0.f, 0.f, 0.f};
#pragma unroll
    for (int dt = 0; dt < 4; dt++) { Ota[dt] = zero; Otb[dt] = zero; }
    lacc_a = zero; lacc_b = zero;
    const f16x8 ones8 = {(f16)1.f, (f16)1.f, (f16)1.f, (f16)1.f,
                         (f16)1.f, (f16)1.f, (f16)1.f, (f16)1.f};

    const int swz = (lr & 7) << 4;

    // prologue: stage tile hn into buf 0; drain before first compute
#pragma unroll
    for (int u = 0; u < 2; u++) gload16(kq[u] + (size_t)hn * 4096, ldsKw + u * 4096);
#pragma unroll
    for (int u = 0; u < 2; u++) gload16(vq[u] + hn * 64, ldsVw + u * 4096);
    asm volatile("s_waitcnt vmcnt(0)" ::: "memory");
    __builtin_amdgcn_s_barrier();

    for (int t = 0; t < 16; t++) {
        {   // issue tile t+1 into the other buffers (fly during compute)
            const int tn = hn + ((t + 1) & 15);
            char* vdst = ldsVw + ((t + 1) & 1) * 8192;
            char* kdst = ldsKw + ((t + 1) & 1) * 8192;
#pragma unroll
            for (int u = 0; u < 2; u++) gload16(vq[u] + tn * 64, vdst + u * 4096);
#pragma unroll
            for (int u = 0; u < 2; u++) gload16(kq[u] + (size_t)tn * 4096, kdst + u * 4096);
        }

        const char* Kb = sKbf + (t & 1) * 8192;
        const char* Vb = sVbf + (t & 1) * 8192;

        f32x4 sta[4], stb[4];
        __builtin_amdgcn_s_setprio(1);
#pragma unroll
        for (int ct = 0; ct < 4; ct++) {
            int row = ct * 16 + lr;
            f16x8 kf0 = *(const f16x8*)(Kb + (((row << 7) | (lg << 4)) ^ swz));
            f16x8 kf1 = *(const f16x8*)(Kb + (((row << 7) | 64 | (lg << 4)) ^ swz));
            f32x4 sa = __builtin_amdgcn_mfma_f32_16x16x32_f16(kf0, qfa0, zero, 0, 0, 0);
            sta[ct]  = __builtin_amdgcn_mfma_f32_16x16x32_f16(kf1, qfa1, sa, 0, 0, 0);
            f32x4 sb = __builtin_amdgcn_mfma_f32_16x16x32_f16(kf0, qfb0, zero, 0, 0, 0);
            stb[ct]  = __builtin_amdgcn_mfma_f32_16x16x32_f16(kf1, qfb1, sb, 0, 0, 0);
        }
        __builtin_amdgcn_s_setprio(0);

        f16x4 ppa[4], ppb[4];
#pragma unroll
        for (int ct = 0; ct < 4; ct++)
#pragma unroll
            for (int r = 0; r < 4; r++) {
                ppa[ct][r] = (f16)__builtin_amdgcn_exp2f(sta[ct][r]);
                ppb[ct][r] = (f16)__builtin_amdgcn_exp2f(stb[ct][r]);
            }

        __builtin_amdgcn_s_setprio(1);
#pragma unroll
        for (int c = 0; c < 2; c++) {
            f16x8 bfa = __builtin_shufflevector(ppa[2 * c], ppa[2 * c + 1], 0, 1, 2, 3, 4, 5, 6, 7);
            f16x8 bfb = __builtin_shufflevector(ppb[2 * c], ppb[2 * c + 1], 0, 1, 2, 3, 4, 5, 6, 7);
            lacc_a = __builtin_amdgcn_mfma_f32_16x16x32_f16(ones8, bfa, lacc_a, 0, 0, 0);
            lacc_b = __builtin_amdgcn_mfma_f32_16x16x32_f16(ones8, bfb, lacc_b, 0, 0, 0);
#pragma unroll
            for (int dt = 0; dt < 4; dt++) {
                int row = dt * 16 + lr;
                f16x4 vlo = *(const f16x4*)(Vb + (((row << 7) | (c << 6) | (lg << 3)) ^ swz));
                f16x4 vhi = *(const f16x4*)(Vb + (((row << 7) | (c << 6) | 32 | (lg << 3)) ^ swz));
                f16x8 vf = __builtin_shufflevector(vlo, vhi, 0, 1, 2, 3, 4, 5, 6, 7);
                Ota[dt] = __builtin_amdgcn_mfma_f32_16x16x32_f16(vf, bfa, Ota[dt], 0, 0, 0);
                Otb[dt] = __builtin_amdgcn_mfma_f32_16x16x32_f16(vf, bfb, Otb[dt], 0, 0, 0);
            }
        }
        __builtin_amdgcn_s_setprio(0);

        asm volatile("s_waitcnt vmcnt(0)" ::: "memory");
        __builtin_amdgcn_s_barrier();
    }

    // ---- epilogue: O^T -> LDS [128 q][64 d] f16 (swizzled) -> coalesced rows ----
    {
        char* const eb = sKbf;                  // 16KB; safe: final vmcnt(0)+barrier done
        const int qa = wave * 32 + lr, qbl = qa + 16;
#pragma unroll
        for (int dt = 0; dt < 4; dt++) {
            f16x4 oa, ob;
#pragma unroll
            for (int r = 0; r < 4; r++) {
                oa[r] = (f16)Ota[dt][r];
                ob[r] = (f16)Otb[dt][r];
            }
            const int dof = dt * 32 + lg * 8;   // byte offset of d = dt*16+lg*4
            *(f16x4*)(eb + qa * 128 + (dof ^ ((qa & 7) << 4))) = oa;
            *(f16x4*)(eb + qbl * 128 + (dof ^ ((qbl & 7) << 4))) = ob;
        }
        __syncthreads();
        // 1024 items = 128 q x 8 chunks of 16B; per wave-instruction: 8 full rows (1KB)
#pragma unroll
        for (int it = 0; it < 4; it++) {
            int item = it * 256 + tid;
            int q = item >> 3, c8 = item & 7;
            f16x8 vv = *(const f16x8*)(eb + q * 128 + ((c8 * 16) ^ ((q & 7) << 4)));
            int qg = qblk * 128 + q;
            if (half == 0)
                *(f16x8*)&cat[((size_t)(b * N_ + qg)) * 1024 + h * 128 + c8 * 8] = vv;
            else
                *(f16x8*)&oaccB[((size_t)(bh * N_ + qg)) * 64 + c8 * 8] = vv;
        }
    }
    if (lg == 0) {
        lacc[half * (32 * N_) + bh * N_ + qrow_a] = lacc_a[0];
        lacc[half * (32 * N_) + bh * N_ + qrow_b] = lacc_b[0];
    }
}

// ---------------- combine: cat = (O_A + O_B) / (l_A + l_B) ----------------
__global__ __launch_bounds__(256) void combine_k(
    f16* __restrict__ cat, const f16* __restrict__ oaccB, const float* __restrict__ lacc)
{
    int gi = blockIdx.x * 256 + threadIdx.x;      // 524288 = 65536 rows x 8
    int row = gi >> 3, c8 = gi & 7;
    int bh = row >> 11, q = row & 2047;
    int b = bh >> 3, h = bh & 7;
    float inv = 1.0f / (lacc[row] + lacc[32 * N_ + row]);
    f16* cp = &cat[((size_t)(b * N_ + q)) * 1024 + h * 128 + c8 * 8];
    f16x8 a = *(const f16x8*)cp;
    f16x8 o2 = *(const f16x8*)&oaccB[(size_t)row * 64 + c8 * 8];
    f16x8 o;
#pragma unroll
    for (int i = 0; i < 8; i++) o[i] = (f16)(((float)a[i] + (float)o2[i]) * inv);
    *(f16x8*)cp = o;
}

// ---------------- launch ----------------

extern "C" void kernel_launch(void* const* d_in, const int* in_sizes, int n_in,
                              void* d_out, int out_size, void* d_ws, size_t ws_size,
                              hipStream_t stream) {
    const float* x      = (const float*)d_in[0];
    const float* w_qkvg = (const float*)d_in[1];
    const float* sigma  = (const float*)d_in[2];
    const float* w_out  = (const float*)d_in[3];
    const float* b_out  = (const float*)d_in[4];
    float* out = (float*)d_out;
    char* ws = (char*)d_ws;

    const size_t MB = 1048576;
    f16*   x16  = (f16*)(ws);                // 0-8 MB   (dead after gemm0)
    float* lacc = (float*)(ws);              // 0-0.5 MB (overlays dead x16; attn+)
    f16*   wqT  = (f16*)(ws + 8 * MB);       // 8-10
    f16*   woT  = (f16*)(ws + 10 * MB);      // 10-11
    f16*   qb   = (f16*)(ws + 11 * MB);      // 11-19
    f16*   kb   = (f16*)(ws + 19 * MB);      // 19-27
    f16*   vbT  = (f16*)(ws + 27 * MB);      // 27-35  [bh][dh][n]
    f16*   vs16 = (f16*)(ws + 35 * MB);      // 35-43  vsigma f16
    f16*   cat  = (f16*)(ws + 43 * MB);      // 43-59  [8192][1024]
    f16*   oaccB= (f16*)(ws + 59 * MB);      // 59-67  [32][2048][64]
    if (ws_size < 67 * MB) return;           // scratch guard

    prep_k<<<2432, 256, 0, stream>>>(x, x16, w_qkvg, wqT, w_out, woT);

    gemm0_8ph<<<256, 512, 0, stream>>>(x16, wqT, qb, kb, vbT, vs16);

    attn_gauss_k<<<2048, 256, 0, stream>>>(qb, kb, vbT, vs16, sigma, cat, oaccB, lacc);
    combine_k<<<2048, 256, 0, stream>>>(cat, oaccB, lacc);

    gemm_small<<<1024, 256, 0, stream>>>(cat, woT, 1024, 512, b_out, out);
}

// Round 22
// 108.762 us; speedup vs baseline: 1.0093x; 1.0093x over previous
//
#include <hip/hip_runtime.h>

typedef _Float16 f16;
typedef __attribute__((ext_vector_type(8))) _Float16 f16x8;
typedef __attribute__((ext_vector_type(4))) _Float16 f16x4;
typedef __attribute__((ext_vector_type(4))) float f32x4;

#define B_ 4
#define N_ 2048
#define DIM_ 512
#define H_ 8
#define DH_ 64

// global -> LDS direct (16B per lane). LDS dest must be wave-uniform;
// global src is per-lane (pre-swizzled). Size must be literal 16.
__device__ __forceinline__ void gload16(const void* g, void* l) {
    __builtin_amdgcn_global_load_lds((const __attribute__((address_space(1))) void*)g,
                                     (__attribute__((address_space(3))) void*)l, 16, 0, 0);
}

// ---------------- fused prep: x cvt + both weight transposes (one launch) ----------------
__global__ __launch_bounds__(256) void prep_k(
    const float* __restrict__ x, f16* __restrict__ x16,
    const float* __restrict__ w_qkvg, f16* __restrict__ wqT,
    const float* __restrict__ w_out, f16* __restrict__ woT)
{
    __shared__ f16 tile[64][72];
    const int bid = blockIdx.x;
    const int t = threadIdx.x;
    if (bid < 2048) {
        int i = bid * 256 + t;                 // n8 = 524288
        const float4 a = ((const float4*)x)[i * 2];
        const float4 b = ((const float4*)x)[i * 2 + 1];
        f16x8 o = {(f16)a.x, (f16)a.y, (f16)a.z, (f16)a.w,
                   (f16)b.x, (f16)b.y, (f16)b.z, (f16)b.w};
        ((f16x8*)x16)[i] = o;
        return;
    }
    const float* in; f16* out; int K, N, lb;
    if (bid < 2304) { in = w_qkvg; out = wqT; K = 512; N = 2048; lb = bid - 2048; }
    else            { in = w_out;  out = woT; K = 1024; N = 512;  lb = bid - 2304; }
    const int nbk = K >> 6;
    const int bk = lb % nbk, bn = lb / nbk;
    const int k0 = bk << 6, n0 = bn << 6;
    const int r = t >> 2, q = (t & 3) << 4;
#pragma unroll
    for (int u = 0; u < 4; u++) {
        const float4 v = *(const float4*)&in[(size_t)(k0 + r) * N + n0 + q + u * 4];
        tile[q + u * 4 + 0][r] = (f16)v.x;
        tile[q + u * 4 + 1][r] = (f16)v.y;
        tile[q + u * 4 + 2][r] = (f16)v.z;
        tile[q + u * 4 + 3][r] = (f16)v.w;
    }
    __syncthreads();
#pragma unroll
    for (int u = 0; u < 2; u++) {
        f16x8 o = *(const f16x8*)&tile[r][q + u * 8];
        *(f16x8*)&out[(size_t)(n0 + r) * K + k0 + q + u * 8] = o;
    }
}

// ---------------- qkvg GEMM: 8-phase 256x256 template + LDS-transposed epilogue ----------------
__global__ __launch_bounds__(512, 2) void gemm0_8ph(
    const f16* __restrict__ A, const f16* __restrict__ BT,
    f16* __restrict__ qb, f16* __restrict__ kb, f16* __restrict__ vbT,
    f16* __restrict__ vs16)
{
    __shared__ char lds[131072];
    const int tid = threadIdx.x;
    const int bid = blockIdx.x;                 // 256 blocks = 1/CU
    const int xcd = bid & 7, w = bid >> 3;      // w in [0,32)
    const int m0 = ((xcd << 2) + (w >> 3)) << 8;   // 32 m-blocks of 256
    const int n0 = (w & 7) << 8;                   // 8 n-blocks of 256
    const int sec = (w & 7) >> 1, secHalf = w & 1; // section + head-half of this block
    const int wave = tid >> 6, lane = tid & 63;
    const int wr = wave >> 2, wc = wave & 3;       // 2M x 4N wave grid
    const int lr = lane & 15, lg = lane >> 4;

    f32x4 acc[8][4];
    const f32x4 zero = {0.f, 0.f, 0.f, 0.f};
#pragma unroll
    for (int i = 0; i < 8; i++)
#pragma unroll
        for (int j = 0; j < 4; j++) acc[i][j] = zero;

    const f16* gA[2][2]; const f16* gB[2][2];   // [half][u]
#pragma unroll
    for (int u = 0; u < 2; u++) {
        int c = tid + u * 512;
        int row = c >> 3;
        int e0 = (((c & 7) ^ (row & 7)) << 3);
#pragma unroll
        for (int h = 0; h < 2; h++) {
            gA[h][u] = A + (size_t)(m0 + h * 128 + row) * 512 + e0;
            gB[h][u] = BT + (size_t)(n0 + h * 128 + row) * 512 + e0;
        }
    }
    const int ldst = wave * 1024;

    // prologue: stage K-tile 0 into dbuf 0
#pragma unroll
    for (int h = 0; h < 2; h++)
#pragma unroll
        for (int u = 0; u < 2; u++)
            gload16(gA[h][u], lds + h * 16384 + ldst + u * 8192);
#pragma unroll
    for (int h = 0; h < 2; h++)
#pragma unroll
        for (int u = 0; u < 2; u++)
            gload16(gB[h][u], lds + 65536 + h * 16384 + ldst + u * 8192);

    const int swz = (lr & 7) << 4;
    for (int T = 0; T < 8; T++) {
        const int d = T & 1, d2 = (T + 1) & 1;
        const size_t Tn64 = (size_t)(T + 1) * 64;
        const char* Ab = lds + (d * 2 + wr) * 16384;
        const char* Bb = lds + 65536 + (d * 2 + (wc >> 1)) * 16384;
#pragma unroll
        for (int p = 0; p < 4; p++) {
            const int kh = p >> 1, qr = p & 1;
            if (T < 7) {                        // last tile: nothing left to stage
                if (p < 2) {
#pragma unroll
                    for (int u = 0; u < 2; u++)
                        gload16(gA[p][u] + Tn64, lds + (d2 * 2 + p) * 16384 + ldst + u * 8192);
                } else {
#pragma unroll
                    for (int u = 0; u < 2; u++)
                        gload16(gB[p - 2][u] + Tn64, lds + 65536 + (d2 * 2 + (p - 2)) * 16384 + ldst + u * 8192);
                }
            }
            if (p == 0) {
                if (T < 7) {
                    asm volatile("s_waitcnt vmcnt(2)" ::: "memory");
                } else {
                    asm volatile("s_waitcnt vmcnt(0)" ::: "memory");   // drain: T7 staged nothing
                }
            }
            __builtin_amdgcn_s_barrier();

            f16x8 af[4], bf[4];
            const int ko = (kh * 64 + lg * 16) ^ swz;
#pragma unroll
            for (int i = 0; i < 4; i++)
                af[i] = *(const f16x8*)(Ab + (qr * 64 + i * 16 + lr) * 128 + ko);
#pragma unroll
            for (int j = 0; j < 4; j++)
                bf[j] = *(const f16x8*)(Bb + ((wc & 1) * 64 + j * 16 + lr) * 128 + ko);
            asm volatile("s_waitcnt lgkmcnt(0)" ::: "memory");
            __builtin_amdgcn_sched_barrier(0);
            __builtin_amdgcn_s_setprio(1);
#pragma unroll
            for (int i = 0; i < 4; i++)
#pragma unroll
                for (int j = 0; j < 4; j++)
                    acc[qr * 4 + i][j] = __builtin_amdgcn_mfma_f32_16x16x32_f16(af[i], bf[j], acc[qr * 4 + i][j], 0, 0, 0);
            __builtin_amdgcn_s_setprio(0);
            __builtin_amdgcn_s_barrier();       // also gates epilogue LDS reuse (vmcnt==0 here)
        }
    }

    // ---- epilogue via LDS transpose (128KB = one 256x256 f16 tile) ----
    if (sec != 2) {
        const float scale = (sec == 0) ? 0.1803368801f : 1.0f;
#pragma unroll
        for (int fr = 0; fr < 8; fr++)
#pragma unroll
            for (int j = 0; j < 4; j++) {
                int nl = wc * 64 + j * 16 + lr;
                int mb = wr * 128 + fr * 16 + lg * 4;
#pragma unroll
                for (int r = 0; r < 4; r++) {
                    int m = mb + r;
                    *(f16*)(lds + m * 512 + ((nl * 2) ^ ((m & 7) << 4))) = (f16)(acc[fr][j][r] * scale);
                }
            }
        __syncthreads();
        f16* dst = (sec == 0) ? qb : (sec == 1 ? kb : vs16);
#pragma unroll
        for (int it = 0; it < 16; it++) {
            int ci = it * 512 + tid;
            int m = ci >> 5, nc = ci & 31;
            f16x8 vv = *(const f16x8*)(lds + m * 512 + ((nc * 16) ^ ((m & 7) << 4)));
            int n = nc * 8;
            int h = secHalf * 4 + (n >> 6), dd = n & 63;
            int gm = m0 + m, b = gm >> 11, ns = gm & 2047;
            *(f16x8*)&dst[((size_t)(b * H_ + h) * N_ + ns) * DH_ + dd] = vv;
        }
    } else {
#pragma unroll
        for (int fr = 0; fr < 8; fr++)
#pragma unroll
            for (int j = 0; j < 4; j++) {
                int n = wc * 64 + j * 16 + lr;
                int mb = wr * 128 + fr * 16 + lg * 4;
                f16x4 o;
#pragma unroll
                for (int r = 0; r < 4; r++) o[r] = (f16)acc[fr][j][r];
                *(f16x4*)(lds + n * 512 + ((mb * 2) ^ ((n & 7) << 4))) = o;
            }
        __syncthreads();
#pragma unroll
        for (int it = 0; it < 16; it++) {
            int ci = it * 512 + tid;
            int n = ci >> 5, mc = ci & 31;
            f16x8 vv = *(const f16x8*)(lds + n * 512 + ((mc * 16) ^ ((n & 7) << 4)));
            int h = secHalf * 4 + (n >> 6), dd = n & 63;
            int gm = m0 + mc * 8, b = gm >> 11, ns = gm & 2047;
            *(f16x8*)&vbT[((size_t)(b * H_ + h) * DH_ + dd) * N_ + ns] = vv;
        }
    }
}

// ---------------- small-N GEMM (final projection): 64x64 tile, BK=128 ----------------
__global__ __launch_bounds__(256) void gemm_small(
    const f16* __restrict__ A, const f16* __restrict__ BT, int K, int N,
    const float* __restrict__ bias, float* __restrict__ outp)
{
    __shared__ char sAb[16384];   // [64 m][128 k] f16
    __shared__ char sBb[16384];   // [64 n][128 k] f16
    const int tid = threadIdx.x;
    const int bid = blockIdx.x;                 // 1024
    const int xcd = bid & 7, w = bid >> 3;
    const int m0 = ((xcd << 4) + (w >> 3)) << 6;
    const int n0 = (w & 7) << 6;
    const int wave = tid >> 6, lane = tid & 63;
    const int wr = wave >> 1, wc = wave & 1;
    const int lr = lane & 15, lg = lane >> 4;

    f32x4 acc[2][2];
    const f32x4 zero = {0.f, 0.f, 0.f, 0.f};
#pragma unroll
    for (int i = 0; i < 2; i++)
#pragma unroll
        for (int j = 0; j < 2; j++) acc[i][j] = zero;

    const f16* srcA[4]; const f16* srcB[4];
    char* ldsA[4]; char* ldsB[4];
#pragma unroll
    for (int u = 0; u < 4; u++) {
        int c = tid + u * 256;
        int row = c >> 4;
        int e0 = (((c & 15) ^ (row & 7)) << 3);
        srcA[u] = A + (size_t)(m0 + row) * K + e0;
        srcB[u] = BT + (size_t)(n0 + row) * K + e0;
        ldsA[u] = sAb + wave * 1024 + u * 4096;
        ldsB[u] = sBb + wave * 1024 + u * 4096;
    }

    const int swz = (lr & 7) << 4;
    for (int kt = 0; kt < K; kt += 128) {
#pragma unroll
        for (int u = 0; u < 4; u++) {
            gload16(srcA[u], ldsA[u]);
            gload16(srcB[u], ldsB[u]);
            srcA[u] += 128; srcB[u] += 128;
        }
        __syncthreads();
#pragma unroll
        for (int khalf = 0; khalf < 4; khalf++) {
            const int ko = (khalf * 64 + lg * 16) ^ swz;
            f16x8 af[2], bf[2];
#pragma unroll
            for (int i = 0; i < 2; i++)
                af[i] = *(const f16x8*)(sAb + (wr * 32 + i * 16 + lr) * 256 + ko);
#pragma unroll
            for (int j = 0; j < 2; j++)
                bf[j] = *(const f16x8*)(sBb + (wc * 32 + j * 16 + lr) * 256 + ko);
#pragma unroll
            for (int i = 0; i < 2; i++)
#pragma unroll
                for (int j = 0; j < 2; j++)
                    acc[i][j] = __builtin_amdgcn_mfma_f32_16x16x32_f16(af[i], bf[j], acc[i][j], 0, 0, 0);
        }
        __syncthreads();
    }

#pragma unroll
    for (int i = 0; i < 2; i++)
#pragma unroll
        for (int j = 0; j < 2; j++) {
            int col = n0 + wc * 32 + j * 16 + lr;
            int row0 = m0 + wr * 32 + i * 16 + lg * 4;
#pragma unroll
            for (int r = 0; r < 4; r++)
                outp[(size_t)(row0 + r) * N + col] = acc[i][j][r] + bias[col];
        }
}

// ---------------- flash attention (softmax branch), KV-split (R13 body) ----------------
// R19: epilogue routes O^T through LDS (reuse sKbf after the loop's final
// vmcnt(0)+barrier) so cat/oaccB writes become full-row 128B-coalesced f16x8
// stores (1KB/wave-instruction) instead of scattered 8B f16x4 stores.
__global__ __launch_bounds__(256) void attn_k(
    const f16* __restrict__ qb, const f16* __restrict__ kb, const f16* __restrict__ vbT,
    f16* __restrict__ cat, f16* __restrict__ oaccB, float* __restrict__ lacc)
{
    __shared__ char sKbf[2 * 8192];   // K bufs, [64 kv][64 dh] f16, swizzled
    __shared__ char sVbf[2 * 8192];   // V bufs, [64 d ][64 kv] f16, swizzled
    const int tid = threadIdx.x;
    const int bid0 = blockIdx.x;
    const int obid = (bid0 & 7) * 128 + (bid0 >> 3);   // bijective XCD swizzle (1024 = 8*128)
    const int bh = obid >> 5, qblk = (obid >> 1) & 15, half = obid & 1;
    const int b = bh >> 3, h = bh & 7;
    const int hn = half << 4;                          // base kv tile of this half
    const int wave = tid >> 6, lane = tid & 63;
    const int lr = lane & 15, lg = lane >> 4;

    const size_t base = (size_t)bh * N_ * DH_;
    const int qrow_a = qblk * 128 + wave * 32 + lr;
    const int qrow_b = qrow_a + 16;
    const f16x8 qfa0 = *(const f16x8*)&qb[base + (size_t)qrow_a * DH_ + lg * 8];
    const f16x8 qfa1 = *(const f16x8*)&qb[base + (size_t)qrow_a * DH_ + 32 + lg * 8];
    const f16x8 qfb0 = *(const f16x8*)&qb[base + (size_t)qrow_b * DH_ + lg * 8];
    const f16x8 qfb1 = *(const f16x8*)&qb[base + (size_t)qrow_b * DH_ + 32 + lg * 8];

    const f16* kq[2]; const f16* vq[2];
#pragma unroll
    for (int u = 0; u < 2; u++) {
        int row = wave * 8 + u * 32 + (lane >> 3);
        int e0 = ((lane & 7) ^ (row & 7)) << 3;
        kq[u] = kb + base + (size_t)row * 64 + e0;
        vq[u] = vbT + base + (size_t)row * 2048 + e0;
    }
    char* const ldsKw = sKbf + wave * 1024;
    char* const ldsVw = sVbf + wave * 1024;

    f32x4 Ota[4], Otb[4], lacc_a, lacc_b;
    const f32x4 zero = {0.f, 0.f, 0.f, 0.f};
#pragma unroll
    for (int dt = 0; dt < 4; dt++) { Ota[dt] = zero; Otb[dt] = zero; }
    lacc_a = zero; lacc_b = zero;
    const f16x8 ones8 = {(f16)1.f, (f16)1.f, (f16)1.f, (f16)1.f,
                         (f16)1.f, (f16)1.f, (f16)1.f, (f16)1.f};

    const int swz = (lr & 7) << 4;

    // prologue: stage tile hn into buf 0; drain before first compute
#pragma unroll
    for (int u = 0; u < 2; u++) gload16(kq[u] + (size_t)hn * 4096, ldsKw + u * 4096);
#pragma unroll
    for (int u = 0; u < 2; u++) gload16(vq[u] + hn * 64, ldsVw + u * 4096);
    asm volatile("s_waitcnt vmcnt(0)" ::: "memory");
    __builtin_amdgcn_s_barrier();

    for (int t = 0; t < 16; t++) {
        {   // issue tile t+1 into the other buffers (fly during compute)
            const int tn = hn + ((t + 1) & 15);
            char* vdst = ldsVw + ((t + 1) & 1) * 8192;
            char* kdst = ldsKw + ((t + 1) & 1) * 8192;
#pragma unroll
            for (int u = 0; u < 2; u++) gload16(vq[u] + tn * 64, vdst + u * 4096);
#pragma unroll
            for (int u = 0; u < 2; u++) gload16(kq[u] + (size_t)tn * 4096, kdst + u * 4096);
        }

        const char* Kb = sKbf + (t & 1) * 8192;
        const char* Vb = sVbf + (t & 1) * 8192;

        f32x4 sta[4], stb[4];
        __builtin_amdgcn_s_setprio(1);
#pragma unroll
        for (int ct = 0; ct < 4; ct++) {
            int row = ct * 16 + lr;
            f16x8 kf0 = *(const f16x8*)(Kb + (((row << 7) | (lg << 4)) ^ swz));
            f16x8 kf1 = *(const f16x8*)(Kb + (((row << 7) | 64 | (lg << 4)) ^ swz));
            f32x4 sa = __builtin_amdgcn_mfma_f32_16x16x32_f16(kf0, qfa0, zero, 0, 0, 0);
            sta[ct]  = __builtin_amdgcn_mfma_f32_16x16x32_f16(kf1, qfa1, sa, 0, 0, 0);
            f32x4 sb = __builtin_amdgcn_mfma_f32_16x16x32_f16(kf0, qfb0, zero, 0, 0, 0);
            stb[ct]  = __builtin_amdgcn_mfma_f32_16x16x32_f16(kf1, qfb1, sb, 0, 0, 0);
        }
        __builtin_amdgcn_s_setprio(0);

        f16x4 ppa[4], ppb[4];
#pragma unroll
        for (int ct = 0; ct < 4; ct++)
#pragma unroll
            for (int r = 0; r < 4; r++) {
                ppa[ct][r] = (f16)__builtin_amdgcn_exp2f(sta[ct][r]);
                ppb[ct][r] = (f16)__builtin_amdgcn_exp2f(stb[ct][r]);
            }

        __builtin_amdgcn_s_setprio(1);
#pragma unroll
        for (int c = 0; c < 2; c++) {
            f16x8 bfa = __builtin_shufflevector(ppa[2 * c], ppa[2 * c + 1], 0, 1, 2, 3, 4, 5, 6, 7);
            f16x8 bfb = __builtin_shufflevector(ppb[2 * c], ppb[2 * c + 1], 0, 1, 2, 3, 4, 5, 6, 7);
            lacc_a = __builtin_amdgcn_mfma_f32_16x16x32_f16(ones8, bfa, lacc_a, 0, 0, 0);
            lacc_b = __builtin_amdgcn_mfma_f32_16x16x32_f16(ones8, bfb, lacc_b, 0, 0, 0);
#pragma unroll
            for (int dt = 0; dt < 4; dt++) {
                int row = dt * 16 + lr;
                f16x4 vlo = *(const f16x4*)(Vb + (((row << 7) | (c << 6) | (lg << 3)) ^ swz));
                f16x4 vhi = *(const f16x4*)(Vb + (((row << 7) | (c << 6) | 32 | (lg << 3)) ^ swz));
                f16x8 vf = __builtin_shufflevector(vlo, vhi, 0, 1, 2, 3, 4, 5, 6, 7);
                Ota[dt] = __builtin_amdgcn_mfma_f32_16x16x32_f16(vf, bfa, Ota[dt], 0, 0, 0);
                Otb[dt] = __builtin_amdgcn_mfma_f32_16x16x32_f16(vf, bfb, Otb[dt], 0, 0, 0);
            }
        }
        __builtin_amdgcn_s_setprio(0);

        asm volatile("s_waitcnt vmcnt(0)" ::: "memory");
        __builtin_amdgcn_s_barrier();
    }

    // ---- epilogue: O^T -> LDS [128 q][64 d] f16 (swizzled) -> coalesced rows ----
    {
        char* const eb = sKbf;                  // 16KB; safe: final vmcnt(0)+barrier done
        const int qa = wave * 32 + lr, qbl = qa + 16;
#pragma unroll
        for (int dt = 0; dt < 4; dt++) {
            f16x4 oa, ob;
#pragma unroll
            for (int r = 0; r < 4; r++) {
                oa[r] = (f16)Ota[dt][r];
                ob[r] = (f16)Otb[dt][r];
            }
            const int dof = dt * 32 + lg * 8;   // byte offset of d = dt*16+lg*4
            *(f16x4*)(eb + qa * 128 + (dof ^ ((qa & 7) << 4))) = oa;
            *(f16x4*)(eb + qbl * 128 + (dof ^ ((qbl & 7) << 4))) = ob;
        }
        __syncthreads();
        // 1024 items = 128 q x 8 chunks of 16B; per wave-instruction: 8 full rows (1KB)
#pragma unroll
        for (int it = 0; it < 4; it++) {
            int item = it * 256 + tid;
            int q = item >> 3, c8 = item & 7;
            f16x8 vv = *(const f16x8*)(eb + q * 128 + ((c8 * 16) ^ ((q & 7) << 4)));
            int qg = qblk * 128 + q;
            if (half == 0)
                *(f16x8*)&cat[((size_t)(b * N_ + qg)) * 1024 + h * 128 + c8 * 8] = vv;
            else
                *(f16x8*)&oaccB[((size_t)(bh * N_ + qg)) * 64 + c8 * 8] = vv;
        }
    }
    if (lg == 0) {
        lacc[half * (32 * N_) + bh * N_ + qrow_a] = lacc_a[0];
        lacc[half * (32 * N_) + bh * N_ + qrow_b] = lacc_b[0];
    }
}

// ---------------- Gaussian branch + attention combine, fused ----------------
__global__ __launch_bounds__(256) void gauss_combine_k(
    const f16* __restrict__ vs16, const float* __restrict__ sigma, f16* __restrict__ cat,
    const f16* __restrict__ oaccB, const float* __restrict__ lacc)
{
    const int tid = threadIdx.x;
    const int bh = blockIdx.y, b = bh >> 3, h = bh & 7;
    const int i0 = blockIdx.x * 64;
    const int wv = tid >> 6, d = tid & 63;
    const float sig = sigma[h];
    const float c = 0.72134752f / (sig * sig);   // log2(e)/(2 sig^2)

    float wt[17];
#pragma unroll
    for (int o = 0; o <= 16; o++) wt[o] = __builtin_amdgcn_exp2f(-(float)(o * o) * c);
    float wfull = wt[0];
#pragma unroll
    for (int o = 1; o <= 16; o++) wfull += 2.f * wt[o];
    const float inv_wfull = 1.0f / wfull;

    const size_t base = (size_t)bh * N_ * DH_;
    const int r0 = i0 + wv * 16 - 16;
    float v[48];
#pragma unroll
    for (int k = 0; k < 48; k++) {
        int r = r0 + k; r = r < 0 ? 0 : (r > N_ - 1 ? N_ - 1 : r);
        v[k] = (float)vs16[base + (size_t)r * DH_ + d];
    }

#pragma unroll
    for (int it = 0; it < 16; it++) {
        int i = i0 + wv * 16 + it;
        float acc = 0.f;
        if (i >= 16 && i <= N_ - 17) {
#pragma unroll
            for (int o = -16; o <= 16; o++)
                acc += wt[o < 0 ? -o : o] * v[16 + it + o];
            acc *= inv_wfull;
        } else {
            float ws = 0.f;
#pragma unroll
            for (int o = -16; o <= 16; o++) {
                int j = i + o;
                if (j >= 0 && j <= N_ - 1) {
                    float w = wt[o < 0 ? -o : o];
                    ws += w;
                    acc += w * v[16 + it + o];
                }
            }
            acc /= ws;
        }
        cat[((size_t)(b * N_ + i)) * 1024 + h * 128 + 64 + d] = (f16)acc;
    }

    // ---- combine for the same 64 rows (cols h*128 + 0..63) ----
#pragma unroll
    for (int it = 0; it < 2; it++) {
        int item = it * 256 + tid;                 // 512 = 64 rows x 8 chunks
        int q = i0 + (item >> 3), c8 = item & 7;
        int row = bh * N_ + q;
        float inv = 1.0f / (lacc[row] + lacc[32 * N_ + row]);
        f16* cp = &cat[((size_t)(b * N_ + q)) * 1024 + h * 128 + c8 * 8];
        f16x8 a = *(const f16x8*)cp;
        f16x8 o2 = *(const f16x8*)&oaccB[(size_t)row * 64 + c8 * 8];
        f16x8 o;
#pragma unroll
        for (int i = 0; i < 8; i++) o[i] = (f16)(((float)a[i] + (float)o2[i]) * inv);
        *(f16x8*)cp = o;
    }
}

// ---------------- launch ----------------

extern "C" void kernel_launch(void* const* d_in, const int* in_sizes, int n_in,
                              void* d_out, int out_size, void* d_ws, size_t ws_size,
                              hipStream_t stream) {
    const float* x      = (const float*)d_in[0];
    const float* w_qkvg = (const float*)d_in[1];
    const float* sigma  = (const float*)d_in[2];
    const float* w_out  = (const float*)d_in[3];
    const float* b_out  = (const float*)d_in[4];
    float* out = (float*)d_out;
    char* ws = (char*)d_ws;

    const size_t MB = 1048576;
    f16*   x16  = (f16*)(ws);                // 0-8 MB   (dead after gemm0)
    float* lacc = (float*)(ws);              // 0-0.5 MB (overlays dead x16; attn+)
    f16*   wqT  = (f16*)(ws + 8 * MB);       // 8-10
    f16*   woT  = (f16*)(ws + 10 * MB);      // 10-11
    f16*   qb   = (f16*)(ws + 11 * MB);      // 11-19
    f16*   kb   = (f16*)(ws + 19 * MB);      // 19-27
    f16*   vbT  = (f16*)(ws + 27 * MB);      // 27-35  [bh][dh][n]
    f16*   vs16 = (f16*)(ws + 35 * MB);      // 35-43  vsigma f16
    f16*   cat  = (f16*)(ws + 43 * MB);      // 43-59  [8192][1024]
    f16*   oaccB= (f16*)(ws + 59 * MB);      // 59-67  [32][2048][64]
    if (ws_size < 67 * MB) return;           // scratch guard

    prep_k<<<2432, 256, 0, stream>>>(x, x16, w_qkvg, wqT, w_out, woT);

    gemm0_8ph<<<256, 512, 0, stream>>>(x16, wqT, qb, kb, vbT, vs16);

    attn_k<<<1024, 256, 0, stream>>>(qb, kb, vbT, cat, oaccB, lacc);
    gauss_combine_k<<<dim3(32, 32), 256, 0, stream>>>(vs16, sigma, cat, oaccB, lacc);

    gemm_small<<<1024, 256, 0, stream>>>(cat, woT, 1024, 512, b_out, out);
}